// Round 7
// baseline (302.975 us; speedup 1.0000x reference)
//
#include <hip/hip_runtime.h>

#define N_NODES 10000
#define E_EDGES 640000
#define IN_CH   512
#define OUT_CH  256
#define HALF_CH 128
#define CSR_CAP (E_EDGES + 8 * N_NODES + 64)   // padded capacity + prefetch slack

// XCD-partitioned scatter geometry
#define SCAT_GROUPS     8
#define ROWS_PER_GROUP  1250                   // 10000 / 8
#define SCAT_GPB        125                    // blocks per group (grid = 1000)
#define SCAT_EPB        5120                   // edges per block = 20 * 256 (125*5120 = E)

typedef short bf16x8 __attribute__((ext_vector_type(8)));
typedef float f32x4  __attribute__((ext_vector_type(4)));

__device__ __forceinline__ unsigned short f2b(float f) {
    unsigned int u = __float_as_uint(f);
    return (unsigned short)((u + 0x7FFFu + ((u >> 16) & 1u)) >> 16);
}

// ---------------- degree histogram + CSR sentinel prefill ----------------
__global__ void deg_kernel(const int* __restrict__ row, int* __restrict__ deg,
                           int* __restrict__ csr_col, int E) {
    int e = blockIdx.x * blockDim.x + threadIdx.x;
    if (e < E) atomicAdd(&deg[row[e]], 1);
    int stride = gridDim.x * blockDim.x;
    for (int i = e; i < CSR_CAP; i += stride) csr_col[i] = N_NODES;  // sentinel -> zero row
}

// ---------------- scan: padded exclusive offsets (deg rounded up to x8) + dinv ----------------
__global__ void scan_kernel(const int* __restrict__ deg, int* __restrict__ offs,
                            float* __restrict__ dinv, int n) {
    __shared__ int partial[256];
    int tid = threadIdx.x;
    int per = (n + 255) / 256;
    int start = tid * per;
    int end = start + per; if (end > n) end = n; if (start > n) start = n;
    int s = 0;
    for (int i = start; i < end; i++) {
        int d = deg[i];
        dinv[i] = (d > 0) ? rsqrtf((float)d) : 0.0f;
        s += (d + 7) & ~7;
    }
    partial[tid] = s;
    __syncthreads();
    for (int off = 1; off < 256; off <<= 1) {
        int v = (tid >= off) ? partial[tid - off] : 0;
        __syncthreads();
        partial[tid] += v;
        __syncthreads();
    }
    int base = (tid == 0) ? 0 : partial[tid - 1];
    for (int i = start; i < end; i++) {
        offs[i] = base;
        base += (deg[i] + 7) & ~7;
    }
    if (tid == 255) offs[n] = partial[255];
}

// ---------------- XCD-partitioned edge scatter ----------------
// group g = blockIdx & 7 handles destination rows [1250g, 1250g+1250); each group's 125
// blocks sweep the full edge list. cursor atomics + csr stores stay XCD-local (per the
// blockIdx%8 XCD round-robin heuristic; correctness independent of actual mapping).
__global__ __launch_bounds__(256) void scatter_kernel(const int* __restrict__ row,
                                                      const int* __restrict__ col,
                                                      const int* __restrict__ offs,
                                                      int* __restrict__ cursor,
                                                      int* __restrict__ csr_col) {
    int g  = blockIdx.x & 7;
    int j  = blockIdx.x >> 3;
    int lo = g * ROWS_PER_GROUP;
    int base = j * SCAT_EPB + threadIdx.x;
    #pragma unroll 4
    for (int i = 0; i < 20; i++) {
        int e = base + i * 256;
        int r = row[e];
        if ((unsigned)(r - lo) < (unsigned)ROWS_PER_GROUP) {
            int c = col[e];
            int p = offs[r] + atomicAdd(&cursor[r], 1);
            csr_col[p] = c;
        }
    }
}

// ---------------- bf16 MFMA GEMM with fused fp32->bf16 staging ----------------
// h0[m][c] = sum_k x[m][k]*w[c][k] + b[c]; fp32 full rows + bf16 planar pre-scaled by
// dinv[m]. Planar bf16 buffers are [(N+1)][128] per plane; row N is the zero pad row.
__global__ __launch_bounds__(256) void gemm_mfma(const float* __restrict__ x,
                                                 const float* __restrict__ w,
                                                 const float* __restrict__ bias,
                                                 const float* __restrict__ dinv,
                                                 float* __restrict__ h0,
                                                 unsigned short* __restrict__ h0b, int M) {
    __shared__ unsigned short As[64][72];
    __shared__ unsigned short Bs[128][72];
    int tid = threadIdx.x;
    int wave = tid >> 6, lane = tid & 63, quad = lane >> 4, l16 = lane & 15;
    int row0 = blockIdx.x * 64;
    int plane = blockIdx.y;
    int n0 = plane * 128;
    unsigned short* h0b_p = h0b + (size_t)plane * (N_NODES + 1) * HALF_CH;

    int ar = tid >> 2;
    int aseg = (tid & 3) * 16;
    int br = tid >> 1;
    int bseg = (tid & 1) * 32;

    f32x4 acc[8] = {};
    for (int k0 = 0; k0 < IN_CH; k0 += 64) {
        {
            int gr = row0 + ar;
            if (gr < M) {
                const float4* src = (const float4*)(x + (size_t)gr * IN_CH + k0 + aseg);
                #pragma unroll
                for (int i = 0; i < 4; i++) {
                    float4 v = src[i];
                    ushort4 o;
                    o.x = f2b(v.x); o.y = f2b(v.y); o.z = f2b(v.z); o.w = f2b(v.w);
                    *(ushort4*)&As[ar][aseg + i * 4] = o;
                }
            } else {
                ushort4 z = {0, 0, 0, 0};
                #pragma unroll
                for (int i = 0; i < 4; i++) *(ushort4*)&As[ar][aseg + i * 4] = z;
            }
        }
        {
            const float4* src = (const float4*)(w + (size_t)(n0 + br) * IN_CH + k0 + bseg);
            #pragma unroll
            for (int i = 0; i < 8; i++) {
                float4 v = src[i];
                ushort4 o;
                o.x = f2b(v.x); o.y = f2b(v.y); o.z = f2b(v.z); o.w = f2b(v.w);
                *(ushort4*)&Bs[br][bseg + i * 4] = o;
            }
        }
        __syncthreads();
        #pragma unroll
        for (int kk = 0; kk < 2; kk++) {
            bf16x8 a = *(const bf16x8*)&As[wave * 16 + l16][kk * 32 + quad * 8];
            #pragma unroll
            for (int t = 0; t < 8; t++) {
                bf16x8 b = *(const bf16x8*)&Bs[t * 16 + l16][kk * 32 + quad * 8];
                acc[t] = __builtin_amdgcn_mfma_f32_16x16x32_bf16(a, b, acc[t], 0, 0, 0);
            }
        }
        __syncthreads();
    }
    #pragma unroll
    for (int t = 0; t < 8; t++) {
        int lcol = t * 16 + l16;
        int col_ = n0 + lcol;
        float bv = bias[col_];
        #pragma unroll
        for (int r = 0; r < 4; r++) {
            int grow = row0 + wave * 16 + quad * 4 + r;
            if (grow < M) {
                float v = acc[t][r] + bv;
                h0   [(size_t)grow * OUT_CH + col_] = v;
                h0b_p[(size_t)grow * HALF_CH + lcol] = f2b(v * dinv[grow]);
            }
        }
    }
    // zero the pad row (sentinel gather target) — one block per plane
    if (blockIdx.x == 0 && tid < 64)
        ((unsigned int*)(h0b_p + (size_t)N_NODES * HALF_CH))[tid] = 0u;
}

// ---------------- SpMM over pre-scaled planar bf16 features, 8-aligned padded CSR ----------
// 2 waves per node (one per 128-ch plane). Next group's metadata prefetched ahead of the
// current group's 8 gathers. y = dinv[node] * sum(hb[col_e]).
__global__ __launch_bounds__(256) void spmm_kernel(const unsigned short* __restrict__ hb,
                                                   const int* __restrict__ offs,
                                                   const int* __restrict__ csr_col,
                                                   const float* __restrict__ dinv,
                                                   const float* __restrict__ prev,
                                                   const float* __restrict__ wts, int widx,
                                                   unsigned short* __restrict__ yb_out,
                                                   float* __restrict__ axpy_out,
                                                   unsigned short* __restrict__ axpyb_out,
                                                   int n) {
    int W = (blockIdx.x * blockDim.x + threadIdx.x) >> 6;
    int lane = threadIdx.x & 63;
    int plane = (W >= n) ? 1 : 0;
    int node = W - plane * n;
    if (node >= n) return;
    size_t pstride = (size_t)(n + 1) * HALF_CH;
    const unsigned short* hp = hb + (size_t)plane * pstride;

    int s = offs[node], e = offs[node + 1];   // 8-aligned
    float a0 = 0.f, a1 = 0.f;
    if (s < e) {
        int4 c0 = *(const int4*)(csr_col + s);
        int4 c1 = *(const int4*)(csr_col + s + 4);
        int p = s;
        while (true) {
            int pn = p + 8;
            int4 nx0 = *(const int4*)(csr_col + pn);      // prefetch (slack-safe)
            int4 nx1 = *(const int4*)(csr_col + pn + 4);
            unsigned int v0 = ((const unsigned int*)(hp + (size_t)c0.x * HALF_CH))[lane];
            unsigned int v1 = ((const unsigned int*)(hp + (size_t)c0.y * HALF_CH))[lane];
            unsigned int v2 = ((const unsigned int*)(hp + (size_t)c0.z * HALF_CH))[lane];
            unsigned int v3 = ((const unsigned int*)(hp + (size_t)c0.w * HALF_CH))[lane];
            unsigned int v4 = ((const unsigned int*)(hp + (size_t)c1.x * HALF_CH))[lane];
            unsigned int v5 = ((const unsigned int*)(hp + (size_t)c1.y * HALF_CH))[lane];
            unsigned int v6 = ((const unsigned int*)(hp + (size_t)c1.z * HALF_CH))[lane];
            unsigned int v7 = ((const unsigned int*)(hp + (size_t)c1.w * HALF_CH))[lane];
            a0 += __uint_as_float(v0 << 16) + __uint_as_float(v1 << 16)
                + __uint_as_float(v2 << 16) + __uint_as_float(v3 << 16)
                + __uint_as_float(v4 << 16) + __uint_as_float(v5 << 16)
                + __uint_as_float(v6 << 16) + __uint_as_float(v7 << 16);
            a1 += __uint_as_float(v0 & 0xFFFF0000u) + __uint_as_float(v1 & 0xFFFF0000u)
                + __uint_as_float(v2 & 0xFFFF0000u) + __uint_as_float(v3 & 0xFFFF0000u)
                + __uint_as_float(v4 & 0xFFFF0000u) + __uint_as_float(v5 & 0xFFFF0000u)
                + __uint_as_float(v6 & 0xFFFF0000u) + __uint_as_float(v7 & 0xFFFF0000u);
            c0 = nx0; c1 = nx1; p = pn;
            if (p >= e) break;
        }
    }

    float di = dinv[node];
    float y0 = di * a0, y1 = di * a1;

    size_t pbase = (size_t)plane * pstride + (size_t)node * HALF_CH + 2 * lane;
    size_t padrow = (size_t)plane * pstride + (size_t)n * HALF_CH + 2 * lane;
    if (yb_out) {
        ushort2 o; o.x = f2b(di * y0); o.y = f2b(di * y1);
        *(ushort2*)(yb_out + pbase) = o;
        if (node == 0) { ushort2 z = {0, 0}; *(ushort2*)(yb_out + padrow) = z; }
    }
    if (axpy_out || axpyb_out) {
        float wk = wts[widx];
        size_t fbase = (size_t)node * OUT_CH + plane * HALF_CH + 2 * lane;
        float2 pv = *(const float2*)(prev + fbase);
        float2 o;
        o.x = pv.x + wk * y0;
        o.y = pv.y + wk * y1;
        if (axpy_out) *(float2*)(axpy_out + fbase) = o;
        if (axpyb_out) {
            ushort2 ob; ob.x = f2b(di * o.x); ob.y = f2b(di * o.y);
            *(ushort2*)(axpyb_out + pbase) = ob;
            if (node == 0) { ushort2 z = {0, 0}; *(ushort2*)(axpyb_out + padrow) = z; }
        }
    }
}

extern "C" void kernel_launch(void* const* d_in, const int* in_sizes, int n_in,
                              void* d_out, int out_size, void* d_ws, size_t ws_size,
                              hipStream_t stream) {
    const float* x     = (const float*)d_in[0];
    const int*   ei    = (const int*)d_in[1];   // [2, E]
    const float* lin_w = (const float*)d_in[2]; // [OUT_CH, IN_CH]
    const float* lin_b = (const float*)d_in[3]; // [OUT_CH]
    const float* wts   = (const float*)d_in[4]; // [K]
    float* out = (float*)d_out;

    char* ws = (char*)d_ws;
    size_t off = 0;
    auto alloc = [&](size_t bytes) -> void* {
        void* p = ws + off;
        off += (bytes + 255) & ~(size_t)255;
        return p;
    };
    int*   deg      = (int*)  alloc(N_NODES * 4 * 2); // deg + cursor (one memset)
    int*   cursor   = deg + N_NODES;
    int*   offs     = (int*)  alloc((N_NODES + 1) * 4);
    float* dinv     = (float*)alloc(N_NODES * 4);
    int*   csr_col  = (int*)  alloc((size_t)CSR_CAP * 4);
    float*          h0    = (float*)         alloc((size_t)N_NODES * OUT_CH * 4);
    unsigned short* h0b   = (unsigned short*)alloc((size_t)2 * (N_NODES + 1) * HALF_CH * 2);
    float*          out1  = (float*)         alloc((size_t)N_NODES * OUT_CH * 4);
    unsigned short* out1b = (unsigned short*)alloc((size_t)2 * (N_NODES + 1) * HALF_CH * 2);
    unsigned short* t2b   = (unsigned short*)alloc((size_t)2 * (N_NODES + 1) * HALF_CH * 2);

    hipMemsetAsync(deg, 0, N_NODES * 4 * 2, stream);

    const int* row = ei;
    const int* col = ei + E_EDGES;

    deg_kernel<<<(E_EDGES + 255) / 256, 256, 0, stream>>>(row, deg, csr_col, E_EDGES);
    scan_kernel<<<1, 256, 0, stream>>>(deg, offs, dinv, N_NODES);
    scatter_kernel<<<SCAT_GROUPS * SCAT_GPB, 256, 0, stream>>>(row, col, offs, cursor, csr_col);

    dim3 ggrid((N_NODES + 63) / 64, 2);
    gemm_mfma<<<ggrid, 256, 0, stream>>>(x, lin_w, lin_b, dinv, h0, h0b, N_NODES);

    int sgrid = (2 * N_NODES + 3) / 4; // 2 waves/node, 4 waves/block
    // out1 = h0 + w0 * spmm(h0)
    spmm_kernel<<<sgrid, 256, 0, stream>>>(h0b, offs, csr_col, dinv, h0, wts, 0,
                                           nullptr, out1, out1b, N_NODES);
    // t2 = spmm(out1)
    spmm_kernel<<<sgrid, 256, 0, stream>>>(out1b, offs, csr_col, dinv, nullptr, wts, 0,
                                           t2b, nullptr, nullptr, N_NODES);
    // out = out1 + w1 * spmm(t2)
    spmm_kernel<<<sgrid, 256, 0, stream>>>(t2b, offs, csr_col, dinv, out1, wts, 1,
                                           nullptr, out, nullptr, N_NODES);
}

// Round 8
// 278.925 us; speedup vs baseline: 1.0862x; 1.0862x over previous
//
#include <hip/hip_runtime.h>

#define N_NODES 10000
#define E_EDGES 640000
#define IN_CH   512
#define OUT_CH  256
#define HALF_CH 128
#define CSR_CAP (E_EDGES + 16 * N_NODES + 128)  // x16-padded capacity + prefetch slack
#define G_GEMM_X 157                            // ceil(10000/64)
#define G_GEMM  (G_GEMM_X * 2)                  // x2 planes
#define G_SCAT  625                             // 625*256*4 = 640000 edges

typedef short bf16x8 __attribute__((ext_vector_type(8)));
typedef float f32x4  __attribute__((ext_vector_type(4)));

__device__ __forceinline__ unsigned short f2b(float f) {
    unsigned int u = __float_as_uint(f);
    return (unsigned short)((u + 0x7FFFu + ((u >> 16) & 1u)) >> 16);
}

// ---------------- degree histogram + CSR sentinel prefill ----------------
__global__ void deg_kernel(const int* __restrict__ row, int* __restrict__ deg,
                           int* __restrict__ csr_col, int E) {
    int e = blockIdx.x * blockDim.x + threadIdx.x;
    if (e < E) atomicAdd(&deg[row[e]], 1);
    int stride = gridDim.x * blockDim.x;
    for (int i = e; i < CSR_CAP; i += stride) csr_col[i] = N_NODES;  // sentinel -> zero row
}

// ---------------- scan: padded exclusive offsets (deg rounded up to x16) + dinv ----------------
__global__ void scan_kernel(const int* __restrict__ deg, int* __restrict__ offs,
                            float* __restrict__ dinv, int n) {
    __shared__ int partial[256];
    int tid = threadIdx.x;
    int per = (n + 255) / 256;
    int start = tid * per;
    int end = start + per; if (end > n) end = n; if (start > n) start = n;
    int s = 0;
    for (int i = start; i < end; i++) {
        int d = deg[i];
        dinv[i] = (d > 0) ? rsqrtf((float)d) : 0.0f;
        s += (d + 15) & ~15;
    }
    partial[tid] = s;
    __syncthreads();
    for (int off = 1; off < 256; off <<= 1) {
        int v = (tid >= off) ? partial[tid - off] : 0;
        __syncthreads();
        partial[tid] += v;
        __syncthreads();
    }
    int base = (tid == 0) ? 0 : partial[tid - 1];
    for (int i = start; i < end; i++) {
        offs[i] = base;
        base += (deg[i] + 15) & ~15;
    }
    if (tid == 255) offs[n] = partial[255];
}

// ---------------- fused GEMM (blocks 0..G_GEMM-1) + edge scatter (rest) ----------------
// GEMM: h0[m][c] = sum_k x[m][k]*w[c][k] + b[c]; fp32 full rows + bf16 planar pre-scaled
// by dinv[m]. Planar bf16 buffers are [(N+1)][128] per plane; row N is the zero pad row.
// Scatter: csr_col[offs[r] + cursor[r]++] = c  (4B payload, norm-free CSR).
__global__ __launch_bounds__(256) void gemm_scatter(const float* __restrict__ x,
                                                    const float* __restrict__ w,
                                                    const float* __restrict__ bias,
                                                    const float* __restrict__ dinv,
                                                    float* __restrict__ h0,
                                                    unsigned short* __restrict__ h0b,
                                                    const int* __restrict__ row,
                                                    const int* __restrict__ col,
                                                    const int* __restrict__ offs,
                                                    int* __restrict__ cursor,
                                                    int* __restrict__ csr_col) {
    __shared__ unsigned short As[64][72];
    __shared__ unsigned short Bs[128][72];
    int bid = blockIdx.x;
    int tid = threadIdx.x;
    if (bid >= G_GEMM) {
        // ---- scatter path ----
        int idx = (bid - G_GEMM) * 256 + tid;
        #pragma unroll
        for (int it = 0; it < 4; it++) {
            int e = idx + it * (G_SCAT * 256);
            if (e < E_EDGES) {
                int r = row[e];
                int c = col[e];
                int p = offs[r] + atomicAdd(&cursor[r], 1);
                csr_col[p] = c;
            }
        }
        return;
    }
    // ---- gemm path ----
    int bx = bid % G_GEMM_X;
    int plane = bid / G_GEMM_X;
    int wave = tid >> 6, lane = tid & 63, quad = lane >> 4, l16 = lane & 15;
    int row0 = bx * 64;
    int n0 = plane * 128;
    unsigned short* h0b_p = h0b + (size_t)plane * (N_NODES + 1) * HALF_CH;

    int ar = tid >> 2;
    int aseg = (tid & 3) * 16;
    int br = tid >> 1;
    int bseg = (tid & 1) * 32;

    f32x4 acc[8] = {};
    for (int k0 = 0; k0 < IN_CH; k0 += 64) {
        {
            int gr = row0 + ar;
            if (gr < N_NODES) {
                const float4* src = (const float4*)(x + (size_t)gr * IN_CH + k0 + aseg);
                #pragma unroll
                for (int i = 0; i < 4; i++) {
                    float4 v = src[i];
                    ushort4 o;
                    o.x = f2b(v.x); o.y = f2b(v.y); o.z = f2b(v.z); o.w = f2b(v.w);
                    *(ushort4*)&As[ar][aseg + i * 4] = o;
                }
            } else {
                ushort4 z = {0, 0, 0, 0};
                #pragma unroll
                for (int i = 0; i < 4; i++) *(ushort4*)&As[ar][aseg + i * 4] = z;
            }
        }
        {
            const float4* src = (const float4*)(w + (size_t)(n0 + br) * IN_CH + k0 + bseg);
            #pragma unroll
            for (int i = 0; i < 8; i++) {
                float4 v = src[i];
                ushort4 o;
                o.x = f2b(v.x); o.y = f2b(v.y); o.z = f2b(v.z); o.w = f2b(v.w);
                *(ushort4*)&Bs[br][bseg + i * 4] = o;
            }
        }
        __syncthreads();
        #pragma unroll
        for (int kk = 0; kk < 2; kk++) {
            bf16x8 a = *(const bf16x8*)&As[wave * 16 + l16][kk * 32 + quad * 8];
            #pragma unroll
            for (int t = 0; t < 8; t++) {
                bf16x8 b = *(const bf16x8*)&Bs[t * 16 + l16][kk * 32 + quad * 8];
                acc[t] = __builtin_amdgcn_mfma_f32_16x16x32_bf16(a, b, acc[t], 0, 0, 0);
            }
        }
        __syncthreads();
    }
    #pragma unroll
    for (int t = 0; t < 8; t++) {
        int lcol = t * 16 + l16;
        int col_ = n0 + lcol;
        float bv = bias[col_];
        #pragma unroll
        for (int r = 0; r < 4; r++) {
            int grow = row0 + wave * 16 + quad * 4 + r;
            if (grow < N_NODES) {
                float v = acc[t][r] + bv;
                h0   [(size_t)grow * OUT_CH + col_] = v;
                h0b_p[(size_t)grow * HALF_CH + lcol] = f2b(v * dinv[grow]);
            }
        }
    }
    // zero the pad row (sentinel gather target) — one block per plane
    if (bx == 0 && tid < 64)
        ((unsigned int*)(h0b_p + (size_t)N_NODES * HALF_CH))[tid] = 0u;
}

// ---------------- SpMM: 16 edges in flight, 4 independent accumulator pairs ----------
// 2 waves per node (one per 128-ch plane). x16-padded CSR (sentinels -> zero row).
// y = dinv[node] * sum(hb[col_e]); bf16 outputs pre-scaled by dinv[node] for next hop.
__global__ __launch_bounds__(256) void spmm_kernel(const unsigned short* __restrict__ hb,
                                                   const int* __restrict__ offs,
                                                   const int* __restrict__ csr_col,
                                                   const float* __restrict__ dinv,
                                                   const float* __restrict__ prev,
                                                   const float* __restrict__ wts, int widx,
                                                   unsigned short* __restrict__ yb_out,
                                                   float* __restrict__ axpy_out,
                                                   unsigned short* __restrict__ axpyb_out,
                                                   int n) {
    int W = (blockIdx.x * blockDim.x + threadIdx.x) >> 6;
    int lane = threadIdx.x & 63;
    int plane = (W >= n) ? 1 : 0;
    int node = W - plane * n;
    if (node >= n) return;
    size_t pstride = (size_t)(n + 1) * HALF_CH;
    const unsigned short* hp = hb + (size_t)plane * pstride;

    int s = offs[node], e = offs[node + 1];   // 16-aligned
    float lo[4] = {0.f, 0.f, 0.f, 0.f};
    float hi[4] = {0.f, 0.f, 0.f, 0.f};
    if (s < e) {
        int4 m0 = *(const int4*)(csr_col + s);
        int4 m1 = *(const int4*)(csr_col + s + 4);
        int4 m2 = *(const int4*)(csr_col + s + 8);
        int4 m3 = *(const int4*)(csr_col + s + 12);
        int p = s;
        while (true) {
            int pn = p + 16;
            int4 x0 = *(const int4*)(csr_col + pn);       // prefetch (slack-safe)
            int4 x1 = *(const int4*)(csr_col + pn + 4);
            int4 x2 = *(const int4*)(csr_col + pn + 8);
            int4 x3 = *(const int4*)(csr_col + pn + 12);
            unsigned int v[16];
            v[0]  = ((const unsigned int*)(hp + (size_t)m0.x * HALF_CH))[lane];
            v[1]  = ((const unsigned int*)(hp + (size_t)m0.y * HALF_CH))[lane];
            v[2]  = ((const unsigned int*)(hp + (size_t)m0.z * HALF_CH))[lane];
            v[3]  = ((const unsigned int*)(hp + (size_t)m0.w * HALF_CH))[lane];
            v[4]  = ((const unsigned int*)(hp + (size_t)m1.x * HALF_CH))[lane];
            v[5]  = ((const unsigned int*)(hp + (size_t)m1.y * HALF_CH))[lane];
            v[6]  = ((const unsigned int*)(hp + (size_t)m1.z * HALF_CH))[lane];
            v[7]  = ((const unsigned int*)(hp + (size_t)m1.w * HALF_CH))[lane];
            v[8]  = ((const unsigned int*)(hp + (size_t)m2.x * HALF_CH))[lane];
            v[9]  = ((const unsigned int*)(hp + (size_t)m2.y * HALF_CH))[lane];
            v[10] = ((const unsigned int*)(hp + (size_t)m2.z * HALF_CH))[lane];
            v[11] = ((const unsigned int*)(hp + (size_t)m2.w * HALF_CH))[lane];
            v[12] = ((const unsigned int*)(hp + (size_t)m3.x * HALF_CH))[lane];
            v[13] = ((const unsigned int*)(hp + (size_t)m3.y * HALF_CH))[lane];
            v[14] = ((const unsigned int*)(hp + (size_t)m3.z * HALF_CH))[lane];
            v[15] = ((const unsigned int*)(hp + (size_t)m3.w * HALF_CH))[lane];
            #pragma unroll
            for (int i = 0; i < 16; i++) {
                lo[i & 3] += __uint_as_float(v[i] << 16);
                hi[i & 3] += __uint_as_float(v[i] & 0xFFFF0000u);
            }
            m0 = x0; m1 = x1; m2 = x2; m3 = x3; p = pn;
            if (p >= e) break;
        }
    }
    float a0 = (lo[0] + lo[1]) + (lo[2] + lo[3]);
    float a1 = (hi[0] + hi[1]) + (hi[2] + hi[3]);

    float di = dinv[node];
    float y0 = di * a0, y1 = di * a1;

    size_t pbase = (size_t)plane * pstride + (size_t)node * HALF_CH + 2 * lane;
    size_t padrow = (size_t)plane * pstride + (size_t)n * HALF_CH + 2 * lane;
    if (yb_out) {
        ushort2 o; o.x = f2b(di * y0); o.y = f2b(di * y1);
        *(ushort2*)(yb_out + pbase) = o;
        if (node == 0) { ushort2 z = {0, 0}; *(ushort2*)(yb_out + padrow) = z; }
    }
    if (axpy_out || axpyb_out) {
        float wk = wts[widx];
        size_t fbase = (size_t)node * OUT_CH + plane * HALF_CH + 2 * lane;
        float2 pv = *(const float2*)(prev + fbase);
        float2 o;
        o.x = pv.x + wk * y0;
        o.y = pv.y + wk * y1;
        if (axpy_out) *(float2*)(axpy_out + fbase) = o;
        if (axpyb_out) {
            ushort2 ob; ob.x = f2b(di * o.x); ob.y = f2b(di * o.y);
            *(ushort2*)(axpyb_out + pbase) = ob;
            if (node == 0) { ushort2 z = {0, 0}; *(ushort2*)(axpyb_out + padrow) = z; }
        }
    }
}

extern "C" void kernel_launch(void* const* d_in, const int* in_sizes, int n_in,
                              void* d_out, int out_size, void* d_ws, size_t ws_size,
                              hipStream_t stream) {
    const float* x     = (const float*)d_in[0];
    const int*   ei    = (const int*)d_in[1];   // [2, E]
    const float* lin_w = (const float*)d_in[2]; // [OUT_CH, IN_CH]
    const float* lin_b = (const float*)d_in[3]; // [OUT_CH]
    const float* wts   = (const float*)d_in[4]; // [K]
    float* out = (float*)d_out;

    char* ws = (char*)d_ws;
    size_t off = 0;
    auto alloc = [&](size_t bytes) -> void* {
        void* p = ws + off;
        off += (bytes + 255) & ~(size_t)255;
        return p;
    };
    int*   deg      = (int*)  alloc(N_NODES * 4 * 2); // deg + cursor (one memset)
    int*   cursor   = deg + N_NODES;
    int*   offs     = (int*)  alloc((N_NODES + 1) * 4);
    float* dinv     = (float*)alloc(N_NODES * 4);
    int*   csr_col  = (int*)  alloc((size_t)CSR_CAP * 4);
    float*          h0    = (float*)         alloc((size_t)N_NODES * OUT_CH * 4);
    unsigned short* h0b   = (unsigned short*)alloc((size_t)2 * (N_NODES + 1) * HALF_CH * 2);
    float*          out1  = (float*)         alloc((size_t)N_NODES * OUT_CH * 4);
    unsigned short* out1b = (unsigned short*)alloc((size_t)2 * (N_NODES + 1) * HALF_CH * 2);
    unsigned short* t2b   = (unsigned short*)alloc((size_t)2 * (N_NODES + 1) * HALF_CH * 2);

    hipMemsetAsync(deg, 0, N_NODES * 4 * 2, stream);

    const int* row = ei;
    const int* col = ei + E_EDGES;

    deg_kernel<<<(E_EDGES + 255) / 256, 256, 0, stream>>>(row, deg, csr_col, E_EDGES);
    scan_kernel<<<1, 256, 0, stream>>>(deg, offs, dinv, N_NODES);

    // fused: GEMM (h0 fp32 + h0b bf16 planar pre-scaled) || CSR scatter
    gemm_scatter<<<G_GEMM + G_SCAT, 256, 0, stream>>>(x, lin_w, lin_b, dinv, h0, h0b,
                                                      row, col, offs, cursor, csr_col);

    int sgrid = (2 * N_NODES + 3) / 4; // 2 waves/node, 4 waves/block
    // out1 = h0 + w0 * spmm(h0)
    spmm_kernel<<<sgrid, 256, 0, stream>>>(h0b, offs, csr_col, dinv, h0, wts, 0,
                                           nullptr, out1, out1b, N_NODES);
    // t2 = spmm(out1)
    spmm_kernel<<<sgrid, 256, 0, stream>>>(out1b, offs, csr_col, dinv, nullptr, wts, 0,
                                           t2b, nullptr, nullptr, N_NODES);
    // out = out1 + w1 * spmm(t2)
    spmm_kernel<<<sgrid, 256, 0, stream>>>(t2b, offs, csr_col, dinv, out1, wts, 1,
                                           nullptr, out, nullptr, N_NODES);
}